// Round 2
// 837.841 us; speedup vs baseline: 1.1696x; 1.1696x over previous
//
#include <hip/hip_runtime.h>

#define BB 512
#define TT 256
#define VV 128
#define EE 64
#define HH 64
#define GG 256   // 4H
#define DD 128   // 2H
#define NN1 512  // 2 dirs * 4H

typedef unsigned short ushort8_t __attribute__((ext_vector_type(8)));
typedef _Float16 h8v __attribute__((ext_vector_type(8)));
typedef float f4v __attribute__((ext_vector_type(4)));

__device__ __forceinline__ float rcpf(float x){ return __builtin_amdgcn_rcpf(x); }
__device__ __forceinline__ float sigf(float x){ return rcpf(1.0f + __expf(-x)); }
__device__ __forceinline__ float tanhfast(float x){ return 1.0f - 2.0f*rcpf(__expf(2.0f*x)+1.0f); }
__device__ __forceinline__ unsigned short f2h(float f){
  union { _Float16 h; unsigned short u; } cv; cv.h = (_Float16)f; return cv.u;
}

// ---------------- prep: embproj tables, f16 weights, exp(trans) ----------------
__global__ void k_prep(const float* __restrict__ emb,
    const float* __restrict__ wih0f, const float* __restrict__ bih0f, const float* __restrict__ bhh0f,
    const float* __restrict__ wih0b, const float* __restrict__ bih0b, const float* __restrict__ bhh0b,
    const float* __restrict__ wih1f, const float* __restrict__ bih1f, const float* __restrict__ bhh1f,
    const float* __restrict__ wih1b, const float* __restrict__ bih1b, const float* __restrict__ bhh1b,
    const float* __restrict__ whh0f, const float* __restrict__ whh0b,
    const float* __restrict__ whh1f, const float* __restrict__ whh1b,
    const float* __restrict__ lin_w, const float* __restrict__ trans, const float* __restrict__ endv,
    float* __restrict__ P0f, float* __restrict__ P0b,
    unsigned short* __restrict__ wB1, unsigned short* __restrict__ linB,
    float* __restrict__ bias1, float* __restrict__ etrans, float* __restrict__ eend,
    unsigned short* __restrict__ whhH)
{
  int bid = blockIdx.x, tid = threadIdx.x;
  if (bid < 256){
    // embproj: P0[d][v][g] = emb[v,:]·wih[g,:] + b_ih[g] + b_hh[g]  (fp32)
    int d = bid >> 7, v = bid & 127;
    const float* wih = d ? wih0b : wih0f;
    const float* bi  = d ? bih0b : bih0f;
    const float* bh  = d ? bhh0b : bhh0f;
    float* P0 = d ? P0b : P0f;
    __shared__ __align__(16) float er[64];
    if (tid < 64) er[tid] = emb[v*64 + tid];
    __syncthreads();
    float acc = bi[tid] + bh[tid];
    const float4* w4 = (const float4*)(wih + tid*64);
    const float4* e4 = (const float4*)er;
    #pragma unroll
    for (int k=0;k<16;k++){
      float4 w = w4[k]; float4 e = e4[k];
      acc += w.x*e.x + w.y*e.y + w.z*e.z + w.w*e.w;
    }
    P0[v*GG + tid] = acc;
  } else if (bid < 320){
    // wB1[n][k] f16, n = dir*256+g over [512], k over [128]
    int e = ((bid-256)*256 + tid)*4;
    int n = e >> 7, k = e & 127;
    const float* w = (n < 256) ? (wih1f + n*128 + k) : (wih1b + (n-256)*128 + k);
    ushort4 o; o.x=f2h(w[0]); o.y=f2h(w[1]); o.z=f2h(w[2]); o.w=f2h(w[3]);
    *(ushort4*)(wB1 + e) = o;
  } else if (bid < 336){
    // linB[v][k] f16 (128 x 128)
    int e = ((bid-320)*256 + tid)*4;
    const float* w = lin_w + e;
    ushort4 o; o.x=f2h(w[0]); o.y=f2h(w[1]); o.z=f2h(w[2]); o.w=f2h(w[3]);
    *(ushort4*)(linB + e) = o;
  } else if (bid < 400){
    int idx = (bid-336)*256 + tid;   // 0..16383
    etrans[idx] = expf(trans[idx]);
  } else if (bid == 400){
    for (int i = tid; i < 512; i += 256){
      int d = i >> 8, gg = i & 255;
      bias1[i] = d ? (bih1b[gg]+bhh1b[gg]) : (bih1f[gg]+bhh1f[gg]);
    }
    if (tid < 128) eend[tid] = expf(endv[tid]);
  } else {
    // whhH: 4 arrays of 256x64 f32 -> f16, order [l0f, l0b, l1f, l1b]
    int blk = bid - 401;             // 0..15
    int arr = blk >> 2;
    int off = (blk & 3)*4096 + tid*16;
    const float* srcs[4] = { whh0f, whh0b, whh1f, whh1b };
    const float* s = srcs[arr];
    #pragma unroll
    for (int u=0;u<16;u+=4){
      float4 v = *(const float4*)(s + off + u);
      unsigned short* dst = whhH + arr*16384 + off + u;
      dst[0]=f2h(v.x); dst[1]=f2h(v.y); dst[2]=f2h(v.z); dst[3]=f2h(v.w);
    }
  }
}

// ---------------- LSTM recurrence via MFMA ----------------
// 64 blocks = 2 dirs x 32 row-groups of 16 batch rows. 4 waves/block; wave w owns
// gate-column slice j in [w*16, w*16+16) => n-tiles {w, w+4, w+8, w+12} so i/f/g/o
// for one (row,j) land in the SAME lane (C layout: row=q*4+r, col=l16 — same
// mapping as the verified k_gemm_mfma). Whh f16 B-frags live in 32 VGPRs/lane;
// c-state in 4 VGPRs. Per step: 2 ds_read_b128 (swizzled) + 8 MFMA + 4-elem gate
// math + 4 ds_write_b16, double-buffered h in LDS => ONE s_barrier per step
// (lgkmcnt-only: global stores / prefetch loads stay in flight across it).
template<int LAYER>
__global__ __launch_bounds__(256)
void k_lstm(const int* __restrict__ x, const float* __restrict__ P0f,
            const float* __restrict__ P0b, const _Float16* __restrict__ pre1,
            const _Float16* __restrict__ whhL, _Float16* __restrict__ hout)
{
  const int bid = blockIdx.x;        // 0..63
  const int dir = bid >> 5;
  const int b0  = (bid & 31) * 16;   // base batch row of this group
  const int tid = threadIdx.x;
  const int wv  = tid >> 6;          // 0..3  (j-slice)
  const int lane = tid & 63;
  const int l16 = lane & 15, q = lane >> 4;
  const int j = wv*16 + l16;         // 0..63 within H
  const int lr0 = q*4;               // local rows lr0..lr0+3

  // B-frags: Whh[n][k], n = gt*64 + j = (gt*4+wv)*16 + l16, k = ks*32 + q*8 .. +7
  const _Float16* whh = whhL + dir*(GG*HH);
  h8v bf[4][2];
  #pragma unroll
  for (int gt=0; gt<4; gt++){
    const int n = gt*64 + j;
    #pragma unroll
    for (int ks=0; ks<2; ks++)
      bf[gt][ks] = *(const h8v*)(whh + n*HH + ks*32 + q*8);
  }

  __shared__ __align__(16) _Float16 hsm[2][16*64];   // double-buffered h tile (2x2KB)
  *(float2*)((char*)hsm + tid*8) = make_float2(0.f, 0.f);  // zero buf0

  const float* P0 = dir ? P0b : P0f;
  const int tt0 = dir ? TT-1 : 0;
  float pc[4][4], pn[4][4];          // pre-activations: current, next
  int xi1[4];
  if (LAYER == 0){
    int xc[4];
    #pragma unroll
    for (int r=0;r<4;r++) xc[r] = x[(b0+lr0+r)*TT + tt0];
    #pragma unroll
    for (int r=0;r<4;r++){
      #pragma unroll
      for (int gt=0;gt<4;gt++) pc[gt][r] = P0[xc[r]*GG + gt*64 + j];
    }
    const int tt1 = dir ? TT-2 : 1;
    #pragma unroll
    for (int r=0;r<4;r++) xi1[r] = x[(b0+lr0+r)*TT + tt1];
  } else {
    const int tt1 = dir ? TT-2 : 1;
    #pragma unroll
    for (int r=0;r<4;r++){
      const size_t base0 = (size_t)((b0+lr0+r)*TT + tt0)*NN1 + dir*GG;
      const size_t base1 = (size_t)((b0+lr0+r)*TT + tt1)*NN1 + dir*GG;
      #pragma unroll
      for (int gt=0;gt<4;gt++){
        pc[gt][r] = (float)pre1[base0 + gt*64 + j];
        pn[gt][r] = (float)pre1[base1 + gt*64 + j];
      }
    }
  }
  float c[4] = {0.f,0.f,0.f,0.f};
  __syncthreads();

  const int swz = (l16 & 7) << 4;    // read-side XOR swizzle (row = l16)
  const char* hbase = (const char*)hsm;
  for (int t=0; t<TT; t++){
    const int tt = dir ? (TT-1-t) : t;
    const int rb = t & 1, wb = rb ^ 1;
    // A-frags: h_prev[m=l16][k = ks*32 + q*8 ..+7], 16B swizzled reads
    h8v a0 = *(const h8v*)(hbase + rb*2048 + ((l16*128 +  0 + q*16) ^ swz));
    h8v a1 = *(const h8v*)(hbase + rb*2048 + ((l16*128 + 64 + q*16) ^ swz));

    // prefetch pre-activations (1 step ahead L0 / 2 steps ahead L1)
    float pn2[4][4];
    int xi2[4];
    if (LAYER == 0){
      if (t < TT-1){
        int tt2 = dir ? (tt-2) : (tt+2);
        tt2 = tt2 < 0 ? 0 : (tt2 > TT-1 ? TT-1 : tt2);
        #pragma unroll
        for (int r=0;r<4;r++){
          const int xv = xi1[r];
          #pragma unroll
          for (int gt=0;gt<4;gt++) pn[gt][r] = P0[xv*GG + gt*64 + j];
          xi2[r] = x[(b0+lr0+r)*TT + tt2];
        }
      }
    } else {
      if (t < TT-2){
        const int ttn = dir ? (tt-2) : (tt+2);
        #pragma unroll
        for (int r=0;r<4;r++){
          const size_t base = (size_t)((b0+lr0+r)*TT + ttn)*NN1 + dir*GG;
          #pragma unroll
          for (int gt=0;gt<4;gt++) pn2[gt][r] = (float)pre1[base + gt*64 + j];
        }
      }
    }

    // recurrent matvec on the matrix pipe
    f4v acc[4];
    #pragma unroll
    for (int gt=0; gt<4; gt++){
      f4v z; z[0]=0.f; z[1]=0.f; z[2]=0.f; z[3]=0.f;
      z       = __builtin_amdgcn_mfma_f32_16x16x32_f16(a0, bf[gt][0], z, 0,0,0);
      acc[gt] = __builtin_amdgcn_mfma_f32_16x16x32_f16(a1, bf[gt][1], z, 0,0,0);
    }

    // gates + state update (4 elements/lane: rows lr0..lr0+3 at column j)
    #pragma unroll
    for (int r=0;r<4;r++){
      const float gi = acc[0][r] + pc[0][r];
      const float gf = acc[1][r] + pc[1][r];
      const float gc = acc[2][r] + pc[2][r];
      const float go = acc[3][r] + pc[3][r];
      const float cn = sigf(gf)*c[r] + sigf(gi)*tanhfast(gc);
      const float hn = sigf(go)*tanhfast(cn);
      c[r] = cn;
      const _Float16 hh = (_Float16)hn;
      const int row = lr0 + r;
      *(_Float16*)((char*)hsm + wb*2048 + ((row*128 + j*2) ^ ((row&7)<<4))) = hh;
      hout[(size_t)((b0+row)*TT + tt)*DD + dir*HH + j] = hh;
    }

    // lgkm-only barrier: LDS writes visible, but vmcnt (hout stores + prefetch
    // loads) stays in flight across the step boundary.
    asm volatile("s_waitcnt lgkmcnt(0)" ::: "memory");
    __builtin_amdgcn_s_barrier();
    asm volatile("" ::: "memory");

    if (t < TT-1){
      #pragma unroll
      for (int r=0;r<4;r++){
        #pragma unroll
        for (int gt=0;gt<4;gt++) pc[gt][r] = pn[gt][r];
      }
      if (LAYER == 0){
        #pragma unroll
        for (int r=0;r<4;r++) xi1[r] = xi2[r];
      } else if (t < TT-2){
        #pragma unroll
        for (int r=0;r<4;r++){
          #pragma unroll
          for (int gt=0;gt<4;gt++) pn[gt][r] = pn2[gt][r];
        }
      }
    }
  }
}

// ---- MFMA GEMM (f16): C[M x N] = A[M x 128] @ B[N x 128]^T + bias ----
// Block tile 128(M) x 64(N), K=128 staged once. 4 waves, wave tile 64x32.
__global__ __launch_bounds__(256, 2)
void k_gemm_mfma(const unsigned short* __restrict__ A, const unsigned short* __restrict__ Bw,
                 const float* __restrict__ bias, void* __restrict__ C,
                 const int N, const int of16)
{
  __shared__ __align__(16) unsigned short As[128*136];
  __shared__ __align__(16) unsigned short Bs[64*136];
  const int tid = threadIdx.x;
  const size_t m0 = (size_t)blockIdx.y * 128;
  const int n0 = blockIdx.x * 64;
  #pragma unroll
  for (int i=0;i<8;i++){
    int idx = tid + i*256;           // 2048 chunks of 8 f16 = 128x128
    int r = idx >> 4, c = idx & 15;
    *(ushort8_t*)(As + r*136 + c*8) = *(const ushort8_t*)(A + (m0+r)*128 + c*8);
  }
  #pragma unroll
  for (int i=0;i<4;i++){
    int idx = tid + i*256;           // 1024 chunks = 64x128
    int r = idx >> 4, c = idx & 15;
    *(ushort8_t*)(Bs + r*136 + c*8) = *(const ushort8_t*)(Bw + (size_t)(n0+r)*128 + c*8);
  }
  __syncthreads();
  const int lane = tid & 63, wid = tid >> 6;
  const int wm = (wid & 1) * 64, wn = (wid >> 1) * 32;
  const int l16 = lane & 15, q = lane >> 4;
  f4v acc[4][2];
  #pragma unroll
  for (int i=0;i<4;i++){
    #pragma unroll
    for (int jj=0;jj<2;jj++){ acc[i][jj][0]=0.f; acc[i][jj][1]=0.f; acc[i][jj][2]=0.f; acc[i][jj][3]=0.f; }
  }
  #pragma unroll
  for (int ks=0; ks<4; ks++){
    const int kb = ks*32 + q*8;
    h8v a[4], b[2];
    #pragma unroll
    for (int mt=0;mt<4;mt++) a[mt] = *(const h8v*)(As + (wm + mt*16 + l16)*136 + kb);
    #pragma unroll
    for (int nt=0;nt<2;nt++) b[nt] = *(const h8v*)(Bs + (wn + nt*16 + l16)*136 + kb);
    #pragma unroll
    for (int mt=0;mt<4;mt++){
      #pragma unroll
      for (int nt=0;nt<2;nt++){
        acc[mt][nt] = __builtin_amdgcn_mfma_f32_16x16x32_f16(a[mt], b[nt], acc[mt][nt], 0, 0, 0);
      }
    }
  }
  #pragma unroll
  for (int mt=0;mt<4;mt++){
    #pragma unroll
    for (int nt=0;nt<2;nt++){
      int col = n0 + wn + nt*16 + l16;
      float bv = bias[col];
      #pragma unroll
      for (int r=0;r<4;r++){
        size_t row = m0 + wm + mt*16 + q*4 + r;
        float v = acc[mt][nt][r] + bv;
        if (of16) ((_Float16*)C)[row*N + col] = (_Float16)v;
        else      ((float*)C)[row*N + col] = v;
      }
    }
  }
}

// ---------------- gold-path score: 1 block (64 thr) per batch row ----------------
__global__ void k_score(const int* __restrict__ x, const int* __restrict__ tags,
                        const float* __restrict__ em, const float* __restrict__ startv,
                        const float* __restrict__ endv, const float* __restrict__ trans,
                        float* __restrict__ score)
{
  int b = blockIdx.x, lane = threadIdx.x;
  float s = 0.f; int cnt = 0;
  for (int t = lane; t < TT; t += 64){
    int xv = x[b*TT + t];
    int m = (xv != 0);
    cnt += m;
    if (t >= 1 && m){
      int tp = tags[b*TT + t - 1], tc = tags[b*TT + t];
      s += trans[tp*VV + tc] + em[(size_t)(b*TT + t)*VV + tc];
    }
  }
  #pragma unroll
  for (int o=32;o>0;o>>=1){ s += __shfl_down(s,o,64); cnt += __shfl_down(cnt,o,64); }
  if (lane==0){
    int t0 = tags[b*TT];
    s += startv[t0] + em[(size_t)(b*TT)*VV + t0];
    int lt = tags[b*TT + cnt - 1];
    s += endv[lt];
    score[b] = s;
  }
}

// ---------------- CRF partition scan in linear domain: 1 block per batch row ----------------
__global__ __launch_bounds__(256,2)
void k_crf(const int* __restrict__ x, const float* __restrict__ em,
           const float* __restrict__ etrans, const float* __restrict__ startv,
           const float* __restrict__ eend, float* __restrict__ part)
{
  const int b = blockIdx.x;
  const int j = threadIdx.x & 127;
  const int ih = threadIdx.x >> 7;     // i-range half
  const int wid = threadIdx.x >> 6;
  const int lane = threadIdx.x & 63;
  float et[64];
  #pragma unroll
  for (int u=0;u<64;u++) et[u] = etrans[(ih*64+u)*VV + j];
  __shared__ __align__(16) float abuf[128];
  __shared__ float spbuf[128];
  __shared__ float red[4];
  float L = 0.f, myA = 0.f;
  {
    float e = 0.f;
    if (ih==0){
      e = __expf(startv[j] + em[(size_t)(b*TT)*VV + j]);
      float wsum = e;
      #pragma unroll
      for (int o=32;o>0;o>>=1) wsum += __shfl_down(wsum,o,64);
      if (lane==0) red[wid] = wsum;
    }
    __syncthreads();
    float Z = red[0]+red[1];
    L = logf(Z);
    if (ih==0){ myA = e/Z; abuf[j] = myA; }
    __syncthreads();
  }
  for (int t=1;t<TT;t++){
    if (x[b*TT + t] == 0) break;       // mask is a contiguous prefix
    float emv = 0.f;
    if (ih==0) emv = em[(size_t)(b*TT + t)*VV + j];
    float s = 0.f;
    const float4* av = (const float4*)(abuf + ih*64);
    #pragma unroll
    for (int i4=0;i4<16;i4++){
      float4 a = av[i4];
      s = fmaf(a.x, et[4*i4+0], s);
      s = fmaf(a.y, et[4*i4+1], s);
      s = fmaf(a.z, et[4*i4+2], s);
      s = fmaf(a.w, et[4*i4+3], s);
    }
    if (ih==1) spbuf[j] = s;
    __syncthreads();
    float raw = 0.f;
    if (ih==0){
      raw = (s + spbuf[j]) * __expf(emv);
      float wsum = raw;
      #pragma unroll
      for (int o=32;o>0;o>>=1) wsum += __shfl_down(wsum,o,64);
      if (lane==0) red[wid] = wsum;
    }
    __syncthreads();
    float Zt = red[0]+red[1];
    L += logf(Zt);
    if (ih==0){ myA = raw/Zt; abuf[j] = myA; }
    __syncthreads();
  }
  {
    float v = 0.f;
    if (ih==0){
      v = myA * eend[j];
      #pragma unroll
      for (int o=32;o>0;o>>=1) v += __shfl_down(v,o,64);
      if (lane==0) red[wid] = v;
    }
    __syncthreads();
    if (threadIdx.x==0) part[b] = L + logf(red[0]+red[1]);
  }
}

__global__ void k_final(const float* __restrict__ part, const float* __restrict__ score,
                        float* __restrict__ out)
{
  __shared__ float red[8];
  int tid = threadIdx.x;
  float v = part[tid] - score[tid];
  #pragma unroll
  for (int o=32;o>0;o>>=1) v += __shfl_down(v,o,64);
  if ((tid&63)==0) red[tid>>6] = v;
  __syncthreads();
  if (tid==0){
    float s = 0.f;
    #pragma unroll
    for (int i=0;i<8;i++) s += red[i];
    out[0] = s / (float)BB;
  }
}

extern "C" void kernel_launch(void* const* d_in, const int* in_sizes, int n_in,
                              void* d_out, int out_size, void* d_ws, size_t ws_size,
                              hipStream_t stream)
{
  const int*   x        = (const int*)d_in[0];
  const int*   tags     = (const int*)d_in[1];
  const float* emb      = (const float*)d_in[2];
  const float* w_ih_l0  = (const float*)d_in[3];
  const float* w_hh_l0  = (const float*)d_in[4];
  const float* b_ih_l0  = (const float*)d_in[5];
  const float* b_hh_l0  = (const float*)d_in[6];
  const float* w_ih_l0r = (const float*)d_in[7];
  const float* w_hh_l0r = (const float*)d_in[8];
  const float* b_ih_l0r = (const float*)d_in[9];
  const float* b_hh_l0r = (const float*)d_in[10];
  const float* w_ih_l1  = (const float*)d_in[11];
  const float* w_hh_l1  = (const float*)d_in[12];
  const float* b_ih_l1  = (const float*)d_in[13];
  const float* b_hh_l1  = (const float*)d_in[14];
  const float* w_ih_l1r = (const float*)d_in[15];
  const float* w_hh_l1r = (const float*)d_in[16];
  const float* b_ih_l1r = (const float*)d_in[17];
  const float* b_hh_l1r = (const float*)d_in[18];
  const float* lin_w    = (const float*)d_in[19];
  const float* lin_b    = (const float*)d_in[20];
  const float* crf_start= (const float*)d_in[21];
  const float* crf_end  = (const float*)d_in[22];
  const float* crf_trans= (const float*)d_in[23];

  char* ws = (char*)d_ws;
  float*          P0f    = (float*)(ws + 0);          // 131072 B
  float*          P0b    = (float*)(ws + 131072);     // 131072 B
  unsigned short* wB1    = (unsigned short*)(ws + 262144);  // 512x128 f16 = 131072 B
  unsigned short* linB   = (unsigned short*)(ws + 393216);  // 128x128 f16 = 32768 B
  float*          bias1  = (float*)(ws + 425984);     // 2048 B
  float*          etrans = (float*)(ws + 428032);     // 65536 B
  float*          eend   = (float*)(ws + 493568);     // 512 B
  float*          scoreA = (float*)(ws + 494080);     // 2048 B
  float*          partA  = (float*)(ws + 496128);     // 2048 B
  unsigned short* whhH   = (unsigned short*)(ws + 498176); // 4x256x64 f16 = 131072 B
  const size_t MB1 = 1ull<<20;
  _Float16* hbuf = (_Float16*)(ws + MB1);                    // 32 MiB f16 (B*T*128)
  _Float16* pre1 = (_Float16*)(ws + MB1 + 33554432ull);      // 128 MiB f16 (B*T*512)
  float*    em   = (float*)(ws + MB1 + 33554432ull);         // aliases pre1 (dead by then)

  k_prep<<<dim3(417), dim3(256), 0, stream>>>(
      emb, w_ih_l0,b_ih_l0,b_hh_l0, w_ih_l0r,b_ih_l0r,b_hh_l0r,
      w_ih_l1,b_ih_l1,b_hh_l1, w_ih_l1r,b_ih_l1r,b_hh_l1r,
      w_hh_l0, w_hh_l0r, w_hh_l1, w_hh_l1r,
      lin_w, crf_trans, crf_end,
      P0f,P0b,wB1,linB,bias1,etrans,eend,whhH);

  k_lstm<0><<<dim3(64), dim3(256), 0, stream>>>(
      x, P0f, P0b, pre1, (const _Float16*)whhH, hbuf);

  k_gemm_mfma<<<dim3(8,1024), dim3(256), 0, stream>>>(
      (const unsigned short*)hbuf, wB1, bias1, (void*)pre1, 512, 1);

  k_lstm<1><<<dim3(64), dim3(256), 0, stream>>>(
      x, P0f, P0b, pre1, (const _Float16*)whhH + 2*GG*HH, hbuf);

  k_gemm_mfma<<<dim3(2,1024), dim3(256), 0, stream>>>(
      (const unsigned short*)hbuf, linB, lin_b, (void*)em, 128, 0);

  k_score<<<dim3(512), dim3(64), 0, stream>>>(
      x, tags, em, crf_start, crf_end, crf_trans, scoreA);

  k_crf<<<dim3(512), dim3(256), 0, stream>>>(
      x, em, etrans, crf_start, eend, partA);

  k_final<<<dim3(1), dim3(512), 0, stream>>>(partA, scoreA, (float*)d_out);
}